// Round 6
// baseline (843.269 us; speedup 1.0000x reference)
//
#include <hip/hip_runtime.h>
#include <math.h>

#define VOC 50000
#define EMB 300
#define BSZ 256
#define CTX 6
#define KNEG 10
#define ROW_VECS (VOC / 4)        // 12500 float4 per one-hot row (VOC % 4 == 0)
#define NROWS (BSZ + BSZ * CTX + BSZ * KNEG)   // 4352
#define WAVES_PER_BLOCK 4
#define NBLOCKS ((NROWS + WAVES_PER_BLOCK - 1) / WAVES_PER_BLOCK)   // 1088

// native clang vector type: accepted by __builtin_nontemporal_load
typedef float floatx4 __attribute__((ext_vector_type(4)));

// One WAVE (64 lanes) per one-hot row; 4 independent waves per block, no
// barriers, no LDS. Early-exit check is a wave-internal __any (ballot) at
// 4 KB granularity -> expected read = half a row for valid rows, which is
// the information-theoretic floor for locating the nonzero.
__global__ __launch_bounds__(64 * WAVES_PER_BLOCK) void scan_rows_wave(
        const floatx4* __restrict__ vo,
        const floatx4* __restrict__ vi,
        const floatx4* __restrict__ neg,
        int* __restrict__ out_idx,     // [NROWS]: vo rows, then vi, then neg
        float* __restrict__ out) {
    const int wave = threadIdx.x >> 6;
    const int lane = threadIdx.x & 63;
    const int r = blockIdx.x * WAVES_PER_BLOCK + wave;
    if (r == 0 && lane == 0) *out = 0.0f;   // zero the loss accumulator
    if (r >= NROWS) return;

    const floatx4* __restrict__ row;
    if (r < BSZ)                 row = vo  + (size_t)r * ROW_VECS;
    else if (r < BSZ + BSZ*CTX)  row = vi  + (size_t)(r - BSZ) * ROW_VECS;
    else                         row = neg + (size_t)(r - BSZ - BSZ*CTX) * ROW_VECS;

    // 49 rounds of 256 vectors (4 KB); UNROLL=4 independent loads per lane
    for (int base = 0; base < ROW_VECS; base += 256) {
        floatx4 v[4];
        int     j[4];
#pragma unroll
        for (int u = 0; u < 4; ++u) {
            j[u] = base + u * 64 + lane;
            if (j[u] < ROW_VECS) v[u] = __builtin_nontemporal_load(&row[j[u]]);
            else                 v[u] = (floatx4)(0.f, 0.f, 0.f, 0.f);
        }
        bool hit = false;
        int  col = 0;
#pragma unroll
        for (int u = 0; u < 4; ++u) {
            if (v[u].x != 0.0f || v[u].y != 0.0f || v[u].z != 0.0f || v[u].w != 0.0f) {
                col = j[u] * 4;
                if (v[u].x != 0.0f)      col += 0;
                else if (v[u].y != 0.0f) col += 1;
                else if (v[u].z != 0.0f) col += 2;
                else                     col += 3;
                hit = true;               // at most one lane hits (one-hot)
            }
        }
        if (__any(hit)) {                 // wave-uniform, no barrier needed
            if (hit) out_idx[r] = col;
            return;
        }
    }
    if (lane == 0) out_idx[r] = -1;       // all-zero (padded vi) row
}

__device__ __forceinline__ float log_sigmoid(float x) {
    return fminf(x, 0.0f) - log1pf(expf(-fabsf(x)));   // stable
}

// One wave (64 lanes) per batch element. EMB=300 -> 5 strided chunks per lane.
// Gathers structured for MLP: 6 vi rows branchless, 10 neg rows into
// independent accumulators.
__global__ void cbow_loss_kernel(const int* __restrict__ idx_vo,
                                 const int* __restrict__ idx_vi,
                                 const int* __restrict__ idx_neg,
                                 const float* __restrict__ V,
                                 const float* __restrict__ U,
                                 float* __restrict__ out) {
    const int b = blockIdx.x;
    const int lane = threadIdx.x;   // blockDim.x == 64

    const int ivo = idx_vo[b];
    int ivi[CTX];
#pragma unroll
    for (int c = 0; c < CTX; ++c) ivi[c] = idx_vi[b * CTX + c];
    int ing[KNEG];
#pragma unroll
    for (int k = 0; k < KNEG; ++k) ing[k] = idx_neg[b * KNEG + k];

    int cnt = 0;
    float w[CTX];
    int   safe[CTX];
#pragma unroll
    for (int c = 0; c < CTX; ++c) {
        w[c] = (ivi[c] >= 0) ? 1.0f : 0.0f;
        safe[c] = (ivi[c] >= 0) ? ivi[c] : 0;
        cnt += (ivi[c] >= 0) ? 1 : 0;
    }
    const float inv_cnt = 1.0f / (float)cnt;   // cnt >= 1 (lengths >= 1)

    float vo_e[5] = {0.f, 0.f, 0.f, 0.f, 0.f};
    const float* __restrict__ vrow = V + (long)ivo * EMB;
#pragma unroll
    for (int j = 0; j < 5; ++j) {
        int d = lane + j * 64;
        if (d < EMB) vo_e[j] = vrow[d];
    }

    float vi_e[5] = {0.f, 0.f, 0.f, 0.f, 0.f};
#pragma unroll
    for (int c = 0; c < CTX; ++c) {
        const float* __restrict__ urow = U + (long)safe[c] * EMB;
#pragma unroll
        for (int j = 0; j < 5; ++j) {
            int d = lane + j * 64;
            if (d < EMB) vi_e[j] += w[c] * urow[d];
        }
    }

    float pd[KNEG];
#pragma unroll
    for (int k = 0; k < KNEG; ++k) pd[k] = 0.f;
#pragma unroll
    for (int k = 0; k < KNEG; ++k) {
        const float* __restrict__ urow = U + (long)ing[k] * EMB;
#pragma unroll
        for (int j = 0; j < 5; ++j) {
            int d = lane + j * 64;
            if (d < EMB) pd[k] += vo_e[j] * urow[d];
        }
    }

    float dot = 0.f;
#pragma unroll
    for (int j = 0; j < 5; ++j) dot += vo_e[j] * (vi_e[j] * inv_cnt);
#pragma unroll
    for (int off = 32; off > 0; off >>= 1) dot += __shfl_down(dot, off, 64);

#pragma unroll
    for (int k = 0; k < KNEG; ++k) {
#pragma unroll
        for (int off = 32; off > 0; off >>= 1) pd[k] += __shfl_down(pd[k], off, 64);
    }

    if (lane == 0) {
        float right = 0.f;
#pragma unroll
        for (int k = 0; k < KNEG; ++k) right += log_sigmoid(-pd[k]);
        float left = log_sigmoid(dot);
        atomicAdd(out, -(left + right) * (1.0f / (float)BSZ));
    }
}

extern "C" void kernel_launch(void* const* d_in, const int* in_sizes, int n_in,
                              void* d_out, int out_size, void* d_ws, size_t ws_size,
                              hipStream_t stream) {
    const float* vo  = (const float*)d_in[0];   // [B, VOC]
    const float* vi  = (const float*)d_in[1];   // [B, CTX, VOC]
    const float* neg = (const float*)d_in[2];   // [B, K, VOC]
    const float* V   = (const float*)d_in[3];   // [VOC, EMB]
    const float* U   = (const float*)d_in[4];   // [VOC, EMB]
    float* out = (float*)d_out;

    int* idx_all = (int*)d_ws;                  // [NROWS]: vo | vi | neg
    int* idx_vo  = idx_all;
    int* idx_vi  = idx_all + BSZ;
    int* idx_neg = idx_all + BSZ + BSZ * CTX;

    scan_rows_wave<<<NBLOCKS, 64 * WAVES_PER_BLOCK, 0, stream>>>(
        (const floatx4*)vo, (const floatx4*)vi, (const floatx4*)neg,
        idx_all, out);

    cbow_loss_kernel<<<BSZ, 64, 0, stream>>>(idx_vo, idx_vi, idx_neg, V, U, out);
}

// Round 7
// 840.844 us; speedup vs baseline: 1.0029x; 1.0029x over previous
//
#include <hip/hip_runtime.h>
#include <math.h>

#define VOC 50000
#define EMB 300
#define BSZ 256
#define CTX 6
#define KNEG 10
#define ROW_VECS (VOC / 4)        // 12500 float4 per one-hot row (VOC % 4 == 0)
#define NROWS (BSZ + BSZ * CTX + BSZ * KNEG)   // 4352

// native clang vector type: accepted by __builtin_nontemporal_load
typedef float floatx4 __attribute__((ext_vector_type(4)));

// One 256-thread workgroup per one-hot row (4352 blocks = 17408 waves: max
// latency-hiding concurrency — R6 showed wave-per-row's 4x lower wave count
// regresses). Early-exit once the nonzero is found; UNROLL=4 keeps 4
// independent 16B loads in flight per thread (16 KB/block per flag check).
// Double barrier makes the early-exit race-free: writes to `found` happen
// only before barrier1; reads only between barrier1 and barrier2.
__global__ __launch_bounds__(256) void scan_rows_kernel(
        const floatx4* __restrict__ vo,
        const floatx4* __restrict__ vi,
        const floatx4* __restrict__ neg,
        int* __restrict__ out_idx,     // [NROWS]: vo rows, then vi, then neg
        float* __restrict__ out) {
    const int r = blockIdx.x;
    if (r == 0 && threadIdx.x == 0) *out = 0.0f;   // zero the loss accumulator

    const floatx4* __restrict__ row;
    if (r < BSZ)                 row = vo  + (size_t)r * ROW_VECS;
    else if (r < BSZ + BSZ*CTX)  row = vi  + (size_t)(r - BSZ) * ROW_VECS;
    else                         row = neg + (size_t)(r - BSZ - BSZ*CTX) * ROW_VECS;

    __shared__ int found;
    if (threadIdx.x == 0) found = 0;
    __syncthreads();

    const int t = threadIdx.x;   // 0..255
    for (int base = 0; base < ROW_VECS; base += 1024) {
        floatx4 v[4];
        int     j[4];
#pragma unroll
        for (int u = 0; u < 4; ++u) {
            j[u] = base + u * 256 + t;
            if (j[u] < ROW_VECS) v[u] = __builtin_nontemporal_load(&row[j[u]]);
            else                 v[u] = (floatx4)(0.f, 0.f, 0.f, 0.f);
        }
#pragma unroll
        for (int u = 0; u < 4; ++u) {
            if (v[u].x != 0.0f || v[u].y != 0.0f || v[u].z != 0.0f || v[u].w != 0.0f) {
                int col = j[u] * 4;
                if (v[u].x != 0.0f)      col += 0;
                else if (v[u].y != 0.0f) col += 1;
                else if (v[u].z != 0.0f) col += 2;
                else                     col += 3;
                out_idx[r] = col;         // exactly one nonzero per row
                found = 1;
            }
        }
        __syncthreads();                  // barrier1: publish writes
        if (found) return;                // uniform read
        __syncthreads();                  // barrier2: reads done before next round
    }
    if (t == 0) out_idx[r] = -1;          // all-zero (padded vi) row
}

__device__ __forceinline__ float log_sigmoid(float x) {
    return fminf(x, 0.0f) - log1pf(expf(-fabsf(x)));   // stable
}

// One wave (64 lanes) per batch element. EMB=300 -> 5 strided chunks per lane.
// Gathers structured for MLP: 6 vi rows branchless (weight 0 for padding),
// 10 neg rows into independent accumulators.
__global__ void cbow_loss_kernel(const int* __restrict__ idx_vo,
                                 const int* __restrict__ idx_vi,
                                 const int* __restrict__ idx_neg,
                                 const float* __restrict__ V,
                                 const float* __restrict__ U,
                                 float* __restrict__ out) {
    const int b = blockIdx.x;
    const int lane = threadIdx.x;   // blockDim.x == 64

    const int ivo = idx_vo[b];
    int ivi[CTX];
#pragma unroll
    for (int c = 0; c < CTX; ++c) ivi[c] = idx_vi[b * CTX + c];
    int ing[KNEG];
#pragma unroll
    for (int k = 0; k < KNEG; ++k) ing[k] = idx_neg[b * KNEG + k];

    int cnt = 0;
    float w[CTX];
    int   safe[CTX];
#pragma unroll
    for (int c = 0; c < CTX; ++c) {
        w[c] = (ivi[c] >= 0) ? 1.0f : 0.0f;
        safe[c] = (ivi[c] >= 0) ? ivi[c] : 0;
        cnt += (ivi[c] >= 0) ? 1 : 0;
    }
    const float inv_cnt = 1.0f / (float)cnt;   // cnt >= 1 (lengths >= 1)

    float vo_e[5] = {0.f, 0.f, 0.f, 0.f, 0.f};
    const float* __restrict__ vrow = V + (long)ivo * EMB;
#pragma unroll
    for (int j = 0; j < 5; ++j) {
        int d = lane + j * 64;
        if (d < EMB) vo_e[j] = vrow[d];
    }

    float vi_e[5] = {0.f, 0.f, 0.f, 0.f, 0.f};
#pragma unroll
    for (int c = 0; c < CTX; ++c) {
        const float* __restrict__ urow = U + (long)safe[c] * EMB;
#pragma unroll
        for (int j = 0; j < 5; ++j) {
            int d = lane + j * 64;
            if (d < EMB) vi_e[j] += w[c] * urow[d];
        }
    }

    float pd[KNEG];
#pragma unroll
    for (int k = 0; k < KNEG; ++k) pd[k] = 0.f;
#pragma unroll
    for (int k = 0; k < KNEG; ++k) {
        const float* __restrict__ urow = U + (long)ing[k] * EMB;
#pragma unroll
        for (int j = 0; j < 5; ++j) {
            int d = lane + j * 64;
            if (d < EMB) pd[k] += vo_e[j] * urow[d];
        }
    }

    float dot = 0.f;
#pragma unroll
    for (int j = 0; j < 5; ++j) dot += vo_e[j] * (vi_e[j] * inv_cnt);
#pragma unroll
    for (int off = 32; off > 0; off >>= 1) dot += __shfl_down(dot, off, 64);

#pragma unroll
    for (int k = 0; k < KNEG; ++k) {
#pragma unroll
        for (int off = 32; off > 0; off >>= 1) pd[k] += __shfl_down(pd[k], off, 64);
    }

    if (lane == 0) {
        float right = 0.f;
#pragma unroll
        for (int k = 0; k < KNEG; ++k) right += log_sigmoid(-pd[k]);
        float left = log_sigmoid(dot);
        atomicAdd(out, -(left + right) * (1.0f / (float)BSZ));
    }
}

extern "C" void kernel_launch(void* const* d_in, const int* in_sizes, int n_in,
                              void* d_out, int out_size, void* d_ws, size_t ws_size,
                              hipStream_t stream) {
    const float* vo  = (const float*)d_in[0];   // [B, VOC]
    const float* vi  = (const float*)d_in[1];   // [B, CTX, VOC]
    const float* neg = (const float*)d_in[2];   // [B, K, VOC]
    const float* V   = (const float*)d_in[3];   // [VOC, EMB]
    const float* U   = (const float*)d_in[4];   // [VOC, EMB]
    float* out = (float*)d_out;

    int* idx_all = (int*)d_ws;                  // [NROWS]: vo | vi | neg
    int* idx_vo  = idx_all;
    int* idx_vi  = idx_all + BSZ;
    int* idx_neg = idx_all + BSZ + BSZ * CTX;

    scan_rows_kernel<<<NROWS, 256, 0, stream>>>(
        (const floatx4*)vo, (const floatx4*)vi, (const floatx4*)neg,
        idx_all, out);

    cbow_loss_kernel<<<BSZ, 64, 0, stream>>>(idx_vo, idx_vi, idx_neg, V, U, out);
}